// Round 6
// baseline (86.744 us; speedup 1.0000x reference)
//
#include <hip/hip_runtime.h>
#include <hip/hip_bf16.h>

// Problem constants (from setup_inputs): B=4, N=8192, M=8192, D=3, fp32.
constexpr int B = 4;
constexpr int N = 8192;
constexpr int M = 8192;

constexpr int TN = 256;              // threads per block
constexpr int NQ = 4;                // queries per thread (consecutive rows)
constexpr int QB = TN * NQ;          // 1024 queries per block
constexpr int NTILES = N / QB;       // 8
constexpr int CHUNKS = 64;           // split of M -> grid 2048 = 8 blocks/CU
constexpr int CHUNK = M / CHUNKS;    // 128 points per block (2 KB LDS)

// ---------------------------------------------------------------------------
// Fused kernel. Per block:
//   1. Stage chunk's w[m] = { -2*px, -2*py, -2*pz, ||p||^2 } into LDS (2 KB).
//   2. Each thread owns NQ=4 CONSECUTIVE queries: its 12 components are 3
//      coalesced, 16B-aligned float4 loads (48*tid is 16B-aligned).
//   3. Inner loop: 4 wave-uniform ds_read_b128 (broadcast) amortized over 4
//      queries -> 56 VALU ops (48 FMA + 8 min3) per 16 pairs (3.5/pair).
//   4. d2 = max(min_m(||p||^2 - 2 a.p) + ||a||^2, 0), merged across chunks
//      with atomicMin on the uint view (d2 >= 0 so uint order == float order;
//      out pre-set to 0x7F7F7F7F = 3.39e38f by hipMemsetAsync).
// NQ=4 keeps VGPR ~45 — safely under the 64-VGPR cap of 8 waves/EU (the NQ=8
// round was pressed against the cap and is the suspected regression cause).
// ---------------------------------------------------------------------------
__global__ __launch_bounds__(256, 8) void main_kernel(const float* __restrict__ input,
                                                      const float* __restrict__ point,
                                                      unsigned int* __restrict__ out) {
    const int bid   = blockIdx.x;
    const int chunk = bid % CHUNKS;
    const int ntile = (bid / CHUNKS) % NTILES;
    const int b     = bid / (CHUNKS * NTILES);
    const int tid   = threadIdx.x;
    const int n0    = ntile * QB + NQ * tid;      // first of 4 consecutive rows

    __shared__ float4 wlds[CHUNK];

    // Stage the point chunk (first 128 threads, one point each).
    if (tid < CHUNK) {
        const float* p = point + ((size_t)b * M + (size_t)chunk * CHUNK + tid) * 3;
        const float px = p[0], py = p[1], pz = p[2];
        float4 v;
        v.x = -2.0f * px;
        v.y = -2.0f * py;
        v.z = -2.0f * pz;
        v.w = fmaf(px, px, fmaf(py, py, pz * pz));
        wlds[tid] = v;
    }

    // Coalesced query load: 3 float4s = 12 components of 4 consecutive rows.
    const float4* aq = (const float4*)(input + ((size_t)b * N + n0) * 3);
    const float4 A = aq[0];
    const float4 Bv = aq[1];
    const float4 C = aq[2];

    float a0[NQ], a1[NQ], a2[NQ], r[NQ];
    a0[0] = A.x;  a1[0] = A.y;  a2[0] = A.z;
    a0[1] = A.w;  a1[1] = Bv.x; a2[1] = Bv.y;
    a0[2] = Bv.z; a1[2] = Bv.w; a2[2] = C.x;
    a0[3] = C.y;  a1[3] = C.z;  a2[3] = C.w;
#pragma unroll
    for (int q = 0; q < NQ; ++q) r[q] = 1e30f;

    __syncthreads();

#pragma unroll 2
    for (int m = 0; m < CHUNK; m += 4) {
        const float4 w0 = wlds[m];
        const float4 w1 = wlds[m + 1];
        const float4 w2 = wlds[m + 2];
        const float4 w3 = wlds[m + 3];
#pragma unroll
        for (int q = 0; q < NQ; ++q) {
            float t0 = fmaf(w0.x, a0[q], w0.w);
            t0 = fmaf(w0.y, a1[q], t0);
            t0 = fmaf(w0.z, a2[q], t0);
            float t1 = fmaf(w1.x, a0[q], w1.w);
            t1 = fmaf(w1.y, a1[q], t1);
            t1 = fmaf(w1.z, a2[q], t1);
            float t2 = fmaf(w2.x, a0[q], w2.w);
            t2 = fmaf(w2.y, a1[q], t2);
            t2 = fmaf(w2.z, a2[q], t2);
            float t3 = fmaf(w3.x, a0[q], w3.w);
            t3 = fmaf(w3.y, a1[q], t3);
            t3 = fmaf(w3.z, a2[q], t3);
            r[q] = fminf(r[q], fminf(t0, t1));   // -> v_min3_f32
            r[q] = fminf(r[q], fminf(t2, t3));   // -> v_min3_f32
        }
    }

#pragma unroll
    for (int q = 0; q < NQ; ++q) {
        const float sq_in = fmaf(a0[q], a0[q], fmaf(a1[q], a1[q], a2[q] * a2[q]));
        float d2 = fmaxf(r[q] + sq_in, 0.0f);
        atomicMin(&out[(size_t)b * N + n0 + q], __float_as_uint(d2));
    }
}

extern "C" void kernel_launch(void* const* d_in, const int* in_sizes, int n_in,
                              void* d_out, int out_size, void* d_ws, size_t ws_size,
                              hipStream_t stream) {
    const float* input = (const float*)d_in[0];   // [B, N, 3] fp32
    const float* point = (const float*)d_in[1];   // [B, M, 3] fp32
    unsigned int* out  = (unsigned int*)d_out;    // [B, N] fp32 viewed as uint

    // Init output to 0x7F7F7F7F (3.39e38f). For non-negative floats the uint
    // ordering matches float ordering, so atomicMin(uint) == float min.
    (void)hipMemsetAsync(d_out, 0x7F, (size_t)out_size * sizeof(float), stream);

    const int main_grid = B * NTILES * CHUNKS;    // 2048 blocks
    main_kernel<<<main_grid, 256, 0, stream>>>(input, point, out);
}

// Round 7
// 73.126 us; speedup vs baseline: 1.1862x; 1.1862x over previous
//
#include <hip/hip_runtime.h>
#include <hip/hip_bf16.h>

// Problem constants (from setup_inputs): B=4, N=8192, M=8192, D=3, fp32.
constexpr int B = 4;
constexpr int N = 8192;
constexpr int M = 8192;

constexpr int QT      = 32;            // queries per wave  (MFMA N dim)
constexpr int WAVES   = 4;             // waves per block
constexpr int QB      = QT * WAVES;    // 128 queries per block
constexpr int QTILES  = N / QB;        // 64
constexpr int PCHUNKS = 8;             // point split -> grid 2048 = 8 blocks/CU
constexpr int CHUNK   = M / PCHUNKS;   // 1024 points per block
constexpr int PTILES  = CHUNK / 32;    // 32 MFMAs per wave

typedef __bf16 bf16x8 __attribute__((ext_vector_type(8)));
typedef float  f32x16 __attribute__((ext_vector_type(16)));

union FragU { uint4 u; bf16x8 b; };

// fp32 -> bf16 bits, round-to-nearest-even (finite inputs only).
__device__ __host__ inline unsigned f2bf(float x) {
    unsigned u = __float_as_uint(x);
    return (u + 0x7FFFu + ((u >> 16) & 1u)) >> 16;
}
__device__ inline float bf2f(unsigned b) { return __uint_as_float(b << 16); }
__device__ inline unsigned pk(unsigned lo, unsigned hi) { return lo | (hi << 16); }

// ---------------------------------------------------------------------------
// K-slot packing (one mfma_f32_32x32x16_bf16, A rows = points, B cols = queries):
//   k0..3 : A=(ph0,ph0,pl0,pl0)  B=(ah0,al0,ah0,al0)  -> (ph0+pl0)(ah0+al0)
//   k4..7 : dim 1, same pattern
//   k8..11: dim 2, same pattern
//   k12,13: A=(sh,sl) B=(1,1)   -> ||p||^2   (hi/lo split)
//   k14,15: 0
// with p' = -2p split hi/lo, a split hi/lo, s = ||p||^2 split hi/lo.
// acc[row=point][col=query] = -2 a.p + ||p||^2  (exact to ~2^-16 rel).
// A-frag layout: A[m=lane&31][k=(lane>>5)*8+j]  -> per point two 16B halves.
// ---------------------------------------------------------------------------

// Prep: pack each point's two A-fragment halves into wtab (32 B/point, 1 MB).
__global__ __launch_bounds__(256) void prep_kernel(const float* __restrict__ point,
                                                   uint4* __restrict__ wtab) {
    int i = blockIdx.x * 256 + threadIdx.x;   // 0 .. B*M-1
    if (i >= B * M) return;
    const float p0 = point[3 * i + 0];
    const float p1 = point[3 * i + 1];
    const float p2 = point[3 * i + 2];
    const float v0 = -2.0f * p0, v1 = -2.0f * p1, v2 = -2.0f * p2;
    const unsigned h0 = f2bf(v0), l0 = f2bf(v0 - bf2f(h0));
    const unsigned h1 = f2bf(v1), l1 = f2bf(v1 - bf2f(h1));
    const unsigned h2 = f2bf(v2), l2 = f2bf(v2 - bf2f(h2));
    const float s = fmaf(p0, p0, fmaf(p1, p1, p2 * p2));
    const unsigned sh = f2bf(s), sl = f2bf(s - bf2f(sh));
    uint4 f0, f1;
    f0.x = pk(h0, h0); f0.y = pk(l0, l0); f0.z = pk(h1, h1); f0.w = pk(l1, l1); // k0..7
    f1.x = pk(h2, h2); f1.y = pk(l2, l2); f1.z = pk(sh, sl); f1.w = 0;          // k8..15
    wtab[2 * i + 0] = f0;
    wtab[2 * i + 1] = f1;
}

// Main: one wave = 32 queries vs CHUNK points via PTILES mfmas.
// Per mfma: one coalesced global_load_dwordx4 (A-frag half per lane), one
// mfma, 8 v_min3 (unroll-2). Lane's 16 acc elements = 16 point-rows of its
// query-col -> in-lane min; cross-half (xor 32) shuffle merges the other 16
// rows; atomicMin(uint view) merges chunks (out pre-set to 0x7F7F7F7F).
__global__ __launch_bounds__(256) void main_kernel(const float* __restrict__ input,
                                                   const uint4* __restrict__ wtab,
                                                   unsigned int* __restrict__ out) {
    const int bid    = blockIdx.x;
    const int pchunk = bid % PCHUNKS;
    const int qtile  = (bid / PCHUNKS) % QTILES;
    const int b      = bid / (PCHUNKS * QTILES);
    const int tid    = threadIdx.x;
    const int wave   = tid >> 6;
    const int lane   = tid & 63;
    const int col    = lane & 31;          // A: point row in tile; B: query col
    const int h      = lane >> 5;          // k-half

    // --- B fragment (this lane's query), built once -----------------------
    const int q = qtile * QB + wave * QT + col;        // query index in [0,N)
    const float* a = input + ((size_t)b * N + q) * 3;
    const float a0 = a[0], a1 = a[1], a2 = a[2];
    const float sq_a = fmaf(a0, a0, fmaf(a1, a1, a2 * a2));
    const unsigned ah0 = f2bf(a0), al0 = f2bf(a0 - bf2f(ah0));
    const unsigned ah1 = f2bf(a1), al1 = f2bf(a1 - bf2f(ah1));
    const unsigned ah2 = f2bf(a2), al2 = f2bf(a2 - bf2f(ah2));

    FragU bq;
    const unsigned dA = h ? pk(ah2, al2) : pk(ah0, al0);
    const unsigned dB = h ? 0x3F803F80u  : pk(ah1, al1);   // (1,1) bf16 | dim1
    bq.u.x = dA;
    bq.u.y = dA;
    bq.u.z = dB;
    bq.u.w = h ? 0u : dB;

    // --- main loop over point tiles ---------------------------------------
    const uint4* __restrict__ wp =
        wtab + ((size_t)b * M + (size_t)pchunk * CHUNK) * 2;

    f32x16 cz;
    f32x16 rmin;
#pragma unroll
    for (int i = 0; i < 16; ++i) { cz[i] = 0.0f; rmin[i] = 1e30f; }

    for (int t = 0; t < PTILES; t += 2) {
        FragU fa0, fa1;
        fa0.u = wp[((t * 32 + col) << 1) + h];
        fa1.u = wp[(((t + 1) * 32 + col) << 1) + h];
        f32x16 acc0 = __builtin_amdgcn_mfma_f32_32x32x16_bf16(fa0.b, bq.b, cz, 0, 0, 0);
        f32x16 acc1 = __builtin_amdgcn_mfma_f32_32x32x16_bf16(fa1.b, bq.b, cz, 0, 0, 0);
#pragma unroll
        for (int i = 0; i < 16; ++i)
            rmin[i] = fminf(rmin[i], fminf(acc0[i], acc1[i]));   // -> v_min3_f32
    }

    // --- epilogue: in-lane fold (16 rows) + cross-half (other 16 rows) ----
    float m = rmin[0];
#pragma unroll
    for (int i = 1; i < 16; ++i) m = fminf(m, rmin[i]);
    m = fminf(m, __shfl_xor(m, 32, 64));

    if (lane < 32) {
        const float d2 = fmaxf(m + sq_a, 0.0f);
        atomicMin(&out[(size_t)b * N + q], __float_as_uint(d2));
    }
}

extern "C" void kernel_launch(void* const* d_in, const int* in_sizes, int n_in,
                              void* d_out, int out_size, void* d_ws, size_t ws_size,
                              hipStream_t stream) {
    const float* input = (const float*)d_in[0];   // [B, N, 3] fp32
    const float* point = (const float*)d_in[1];   // [B, M, 3] fp32
    unsigned int* out  = (unsigned int*)d_out;    // [B, N] fp32 viewed as uint

    uint4* wtab = (uint4*)d_ws;                   // 1 MB packed A-fragment table

    // Init output to 0x7F7F7F7F (3.39e38f): uint order == float order for
    // non-negative floats, so atomicMin(uint) implements float min.
    (void)hipMemsetAsync(d_out, 0x7F, (size_t)out_size * sizeof(float), stream);

    const int prep_grid = (B * M + 255) / 256;        // 128 blocks
    const int main_grid = B * QTILES * PCHUNKS;       // 2048 blocks

    prep_kernel<<<prep_grid, 256, 0, stream>>>(point, wtab);
    main_kernel<<<main_grid, 256, 0, stream>>>(input, wtab, out);
}

// Round 8
// 66.046 us; speedup vs baseline: 1.3134x; 1.1072x over previous
//
#include <hip/hip_runtime.h>
#include <hip/hip_bf16.h>

// Problem constants (from setup_inputs): B=4, N=8192, M=8192, D=3, fp32.
constexpr int B = 4;
constexpr int N = 8192;
constexpr int M = 8192;

constexpr int QPW     = 64;            // queries per wave (2 B-fragments)
constexpr int WAVES   = 4;             // waves per block
constexpr int QB      = QPW * WAVES;   // 256 queries per block
constexpr int QTILES  = N / QB;        // 32
constexpr int PCHUNKS = 16;            // point split -> grid 2048 = 8 blocks/CU
constexpr int CHUNK   = M / PCHUNKS;   // 512 points per block
constexpr int PTILES  = CHUNK / 32;    // 16 A-tile loads, 32 mfmas per wave

typedef __bf16 bf16x8 __attribute__((ext_vector_type(8)));
typedef float  f32x16 __attribute__((ext_vector_type(16)));

union FragU { uint4 u; bf16x8 b; };

// fp32 -> bf16 bits, round-to-nearest-even (finite inputs only).
__device__ __host__ inline unsigned f2bf(float x) {
    unsigned u = __float_as_uint(x);
    return (u + 0x7FFFu + ((u >> 16) & 1u)) >> 16;
}
__device__ inline float bf2f(unsigned b) { return __uint_as_float(b << 16); }
__device__ inline unsigned pk(unsigned lo, unsigned hi) { return lo | (hi << 16); }

// ---------------------------------------------------------------------------
// K-slot packing (mfma_f32_32x32x16_bf16, A rows = points, B cols = queries):
//   k0..3 : A=(ph0,ph0,pl0,pl0)  B=(ah0,al0,ah0,al0)  -> (ph0+pl0)(ah0+al0)
//   k4..7 : dim 1   k8..11: dim 2   k12,13: A=(sh,sl) B=(1,1) -> ||p||^2
//   k14,15: 0         (p' = -2p, everything split bf16 hi/lo)
// acc[row=point][col=query] = -2 a.p + ||p||^2   (verified round 7,
// absmax 7.8e-3 vs 6.75e-2 threshold).
// A-frag layout: A[m=lane&31][k=(lane>>5)*8+j] -> 2x16B halves per point.
// ---------------------------------------------------------------------------

// Prep: pack each point's two A-fragment halves into wtab (32 B/point, 1 MB)
// AND initialize out to 0x7F7F7F7F (3.39e38f; uint order == float order for
// non-negative floats, so atomicMin(uint) implements float min). B*M == B*N.
__global__ __launch_bounds__(256) void prep_kernel(const float* __restrict__ point,
                                                   uint4* __restrict__ wtab,
                                                   unsigned int* __restrict__ out) {
    int i = blockIdx.x * 256 + threadIdx.x;   // 0 .. B*M-1
    if (i >= B * M) return;
    const float p0 = point[3 * i + 0];
    const float p1 = point[3 * i + 1];
    const float p2 = point[3 * i + 2];
    const float v0 = -2.0f * p0, v1 = -2.0f * p1, v2 = -2.0f * p2;
    const unsigned h0 = f2bf(v0), l0 = f2bf(v0 - bf2f(h0));
    const unsigned h1 = f2bf(v1), l1 = f2bf(v1 - bf2f(h1));
    const unsigned h2 = f2bf(v2), l2 = f2bf(v2 - bf2f(h2));
    const float s = fmaf(p0, p0, fmaf(p1, p1, p2 * p2));
    const unsigned sh = f2bf(s), sl = f2bf(s - bf2f(sh));
    uint4 f0, f1;
    f0.x = pk(h0, h0); f0.y = pk(l0, l0); f0.z = pk(h1, h1); f0.w = pk(l1, l1); // k0..7
    f1.x = pk(h2, h2); f1.y = pk(l2, l2); f1.z = pk(sh, sl); f1.w = 0;          // k8..15
    wtab[2 * i + 0] = f0;
    wtab[2 * i + 1] = f1;
    out[i] = 0x7F7F7F7Fu;
}

// Build the B fragment for query index q (this lane's column).
__device__ inline FragU make_bfrag(const float* __restrict__ input,
                                   int b, int q, int h, float& sq_a) {
    const float* a = input + ((size_t)b * N + q) * 3;
    const float a0 = a[0], a1 = a[1], a2 = a[2];
    sq_a = fmaf(a0, a0, fmaf(a1, a1, a2 * a2));
    const unsigned ah0 = f2bf(a0), al0 = f2bf(a0 - bf2f(ah0));
    const unsigned ah1 = f2bf(a1), al1 = f2bf(a1 - bf2f(ah1));
    const unsigned ah2 = f2bf(a2), al2 = f2bf(a2 - bf2f(ah2));
    FragU bq;
    const unsigned dA = h ? pk(ah2, al2) : pk(ah0, al0);
    const unsigned dB = h ? 0x3F803F80u  : pk(ah1, al1);   // (1,1) bf16 | dim1
    bq.u.x = dA;
    bq.u.y = dA;
    bq.u.z = dB;
    bq.u.w = h ? 0u : dB;
    return bq;
}

// Main: one wave = 64 queries (2 B frags) vs its 512-point chunk.
// Per 2 A-tile loads: 4 mfmas + 32 v_min3 (8/mfma, optimal). Each A load
// feeds 2 mfmas -> VMEM instructions halved vs round 7 (the round-7 limiter:
// ~16 cyc/TA per 2 KB wave-load).
__global__ __launch_bounds__(256, 3) void main_kernel(const float* __restrict__ input,
                                                      const uint4* __restrict__ wtab,
                                                      unsigned int* __restrict__ out) {
    const int bid    = blockIdx.x;
    const int pchunk = bid % PCHUNKS;
    const int qtile  = (bid / PCHUNKS) % QTILES;
    const int b      = bid / (PCHUNKS * QTILES);
    const int tid    = threadIdx.x;
    const int wave   = tid >> 6;
    const int lane   = tid & 63;
    const int col    = lane & 31;          // A: point row in tile; B: query col
    const int h      = lane >> 5;          // k-half

    const int q0 = qtile * QB + wave * QPW + col;        // first query set
    const int q1 = q0 + 32;                              // second query set
    float sq_a0, sq_a1;
    const FragU b0 = make_bfrag(input, b, q0, h, sq_a0);
    const FragU b1 = make_bfrag(input, b, q1, h, sq_a1);

    const uint4* __restrict__ wp =
        wtab + ((size_t)b * M + (size_t)pchunk * CHUNK) * 2;

    f32x16 cz, rmin0, rmin1;
#pragma unroll
    for (int i = 0; i < 16; ++i) { cz[i] = 0.0f; rmin0[i] = 1e30f; rmin1[i] = 1e30f; }

    for (int t = 0; t < PTILES; t += 2) {
        FragU fa0, fa1;
        fa0.u = wp[((t * 32 + col) << 1) + h];
        fa1.u = wp[(((t + 1) * 32 + col) << 1) + h];
        f32x16 acc00 = __builtin_amdgcn_mfma_f32_32x32x16_bf16(fa0.b, b0.b, cz, 0, 0, 0);
        f32x16 acc01 = __builtin_amdgcn_mfma_f32_32x32x16_bf16(fa0.b, b1.b, cz, 0, 0, 0);
        f32x16 acc10 = __builtin_amdgcn_mfma_f32_32x32x16_bf16(fa1.b, b0.b, cz, 0, 0, 0);
        f32x16 acc11 = __builtin_amdgcn_mfma_f32_32x32x16_bf16(fa1.b, b1.b, cz, 0, 0, 0);
#pragma unroll
        for (int i = 0; i < 16; ++i) {
            rmin0[i] = fminf(rmin0[i], fminf(acc00[i], acc10[i]));   // v_min3_f32
            rmin1[i] = fminf(rmin1[i], fminf(acc01[i], acc11[i]));   // v_min3_f32
        }
    }

    // Epilogue: in-lane fold (16 rows) + cross-half shuffle (other 16 rows).
    float m0 = rmin0[0], m1 = rmin1[0];
#pragma unroll
    for (int i = 1; i < 16; ++i) { m0 = fminf(m0, rmin0[i]); m1 = fminf(m1, rmin1[i]); }
    m0 = fminf(m0, __shfl_xor(m0, 32, 64));
    m1 = fminf(m1, __shfl_xor(m1, 32, 64));

    if (lane < 32) {
        atomicMin(&out[(size_t)b * N + q0], __float_as_uint(fmaxf(m0 + sq_a0, 0.0f)));
        atomicMin(&out[(size_t)b * N + q1], __float_as_uint(fmaxf(m1 + sq_a1, 0.0f)));
    }
}

extern "C" void kernel_launch(void* const* d_in, const int* in_sizes, int n_in,
                              void* d_out, int out_size, void* d_ws, size_t ws_size,
                              hipStream_t stream) {
    const float* input = (const float*)d_in[0];   // [B, N, 3] fp32
    const float* point = (const float*)d_in[1];   // [B, M, 3] fp32
    unsigned int* out  = (unsigned int*)d_out;    // [B, N] fp32 viewed as uint

    uint4* wtab = (uint4*)d_ws;                   // 1 MB packed A-fragment table

    const int prep_grid = (B * M + 255) / 256;        // 128 blocks
    const int main_grid = B * QTILES * PCHUNKS;       // 2048 blocks

    prep_kernel<<<prep_grid, 256, 0, stream>>>(point, wtab, out);
    main_kernel<<<main_grid, 256, 0, stream>>>(input, wtab, out);
}